// Round 3
// baseline (1039.234 us; speedup 1.0000x reference)
//
#include <hip/hip_runtime.h>
#include <hip/hip_bf16.h>
#include <cstdint>
#include <cstddef>

// Problem dims
#define Bn 64
#define Tn 2048
#define Mn 1024   // MEMORY_SIZE (GEMM K)
#define An 512    // ATTN_SIZE
#define Qn 1024   // QUERY_SIZE

#define RT 64     // t-rows per block
#define GK 128    // k per group (4 chunks of 32)
#define NG 8      // groups
#define NCH 32    // 32-k chunks total

typedef __attribute__((ext_vector_type(8))) short short8;
typedef __attribute__((ext_vector_type(4))) float f32x4;
typedef __attribute__((ext_vector_type(2))) float f32x2;
typedef __attribute__((ext_vector_type(4))) unsigned short us4;

static __device__ __forceinline__ unsigned short f2bf(float f) {
  uint32_t u = __float_as_uint(f);
  u += 0x7fff + ((u >> 16) & 1);   // RNE
  return (unsigned short)(u >> 16);
}

// ---------------- prep kernels ----------------
__global__ void zero_kernel(float* __restrict__ ctx, float* __restrict__ Zacc) {
  int i = blockIdx.x * 256 + threadIdx.x;
  if (i < Bn * Mn) ctx[i] = 0.0f;
  else if (i < Bn * Mn + Bn) Zacc[i - Bn * Mn] = 0.0f;
}

__global__ void cvt_wm_kernel(const float* __restrict__ Wm, unsigned short* __restrict__ out) {
  int i = blockIdx.x * 256 + threadIdx.x;
  if (i < An * Mn) out[i] = f2bf(Wm[i]);
}

// w_query[b][a] = sum_m query[b][m] * W_query[a][m]  (fp32 exact, tiny)
__global__ void wq_kernel(const float* __restrict__ query, const float* __restrict__ Wq,
                          float* __restrict__ wqout) {
  __shared__ __align__(16) float qs[Qn];
  const int b = blockIdx.x >> 2;
  const int ag = blockIdx.x & 3;
  const int tid = threadIdx.x;  // 128
  for (int i = tid; i < Qn; i += 128) qs[i] = query[b * Qn + i];
  __syncthreads();
  const int a = ag * 128 + tid;
  const f32x4* w = (const f32x4*)(Wq + (size_t)a * Qn);
  const f32x4* q4 = (const f32x4*)qs;
  float acc = 0.f;
#pragma unroll 8
  for (int m = 0; m < Qn / 4; ++m) {
    f32x4 wv = w[m];
    f32x4 qv = q4[m];
    acc += wv.x * qv.x + wv.y * qv.y + wv.z * qv.z + wv.w * qv.w;
  }
  wqout[b * An + a] = acc;
}

// ---------------- fused main kernel ----------------
// Block = (b, 64-row t-tile), 512 thr = 8 waves; wave w owns cols w*64..+63.
// B (Wmb, L2-hot): per-wave global->register, pipelined one 32-k chunk ahead. NO LDS, no barrier coupling.
// A (memory):  LDS double buffer of 128-k GROUPS (2 x 16 KB); global loads for group g+1 issued
//              1-3 chunks before their ds_write; ONE barrier per group (9 total vs 32).
// LDS 33 KB -> 2+ blocks/CU; XOR-swizzled 16B units keep ds_read_b128/write uniform across banks.
__launch_bounds__(512, 4)
__global__ void fused_kernel(const float* __restrict__ mem,
                             const float* __restrict__ wq,
                             const unsigned short* __restrict__ Wmb,
                             const float* __restrict__ Wv,
                             float* __restrict__ out,
                             float* __restrict__ Zacc,
                             float* __restrict__ partials) {
  __shared__ __align__(16) unsigned short Abuf[2][RT * GK];  // 2 x 16 KB
  __shared__ float s_score[RT];
  __shared__ float s_e[RT];

  const int tid = threadIdx.x;
  const int b  = blockIdx.x & (Bn - 1);
  const int tt = blockIdx.x >> 6;
  const int t0 = tt * RT;

  const int lane = tid & 63;
  const int w = tid >> 6;        // wave -> col slice w*64
  const int l15 = lane & 15;
  const int quad = lane >> 4;

  if (tid < RT) s_score[tid] = 0.f;

  // A staging: thread -> (row = tid>>3, 4-float k-subgroup h = tid&7) within each 32-k chunk
  const int arow = tid >> 3;
  const int ah = tid & 7;
  const float* asrc = mem + ((size_t)(b * Tn + t0 + arow)) * Mn + ah * 4;
  const int w_lu = ah >> 1;        // logical 16B unit within chunk (+ kcl*4)
  const int w_half = (ah & 1) * 4; // ushort offset within unit

  // write chunk kcl of a group buffer; unit swizzle phys = (lu + row) & 15
  auto awr = [&](unsigned short* buf, int kcl, f32x4 v) {
    int off = arow * GK + ((((kcl << 2) + w_lu + arow) & 15) << 3) + w_half;
    us4 o; o.x = f2bf(v.x); o.y = f2bf(v.y); o.z = f2bf(v.z); o.w = f2bf(v.w);
    *(us4*)&buf[off] = o;
  };

  // B fragment base pointers (per col-tile), L2-resident
  const unsigned short* bbase[4];
#pragma unroll
  for (int ct = 0; ct < 4; ++ct)
    bbase[ct] = Wmb + (size_t)(w * 64 + ct * 16 + l15) * Mn + quad * 8;

  // ---- prologue: stage A group 0, load B chunk 0 ----
  {
    f32x4 v0 = *(const f32x4*)(asrc + 0 * 32);
    f32x4 v1 = *(const f32x4*)(asrc + 1 * 32);
    f32x4 v2 = *(const f32x4*)(asrc + 2 * 32);
    f32x4 v3 = *(const f32x4*)(asrc + 3 * 32);
    awr((unsigned short*)Abuf[0], 0, v0);
    awr((unsigned short*)Abuf[0], 1, v1);
    awr((unsigned short*)Abuf[0], 2, v2);
    awr((unsigned short*)Abuf[0], 3, v3);
  }
  short8 bb[2][4];
#pragma unroll
  for (int ct = 0; ct < 4; ++ct) bb[0][ct] = *(const short8*)(bbase[ct]);
  __syncthreads();

  f32x4 acc[4][4] = {};
  f32x4 ap0, ap1, ap2, ap3;

  for (int g = 0; g < NG; ++g) {
    const int base = g * 4;
    unsigned short* nbuf = (unsigned short*)Abuf[(g & 1) ^ 1];
    const unsigned short* cbuf = (const unsigned short*)Abuf[g & 1];
#pragma unroll
    for (int j = 0; j < 4; ++j) {
      const int kc = base + j;
      const int cu = j & 1;        // base is even
      const int nx = cu ^ 1;
      if (kc + 1 < NCH) {          // B pipeline: next chunk into the other reg set
#pragma unroll
        for (int ct = 0; ct < 4; ++ct)
          bb[nx][ct] = *(const short8*)(bbase[ct] + (size_t)(kc + 1) * 32);
      }
      if (g + 1 < NG) {            // A global prefetch for next group (issued early)
        if (j == 0) { ap0 = *(const f32x4*)(asrc + (size_t)(base + 4) * 32);
                      ap1 = *(const f32x4*)(asrc + (size_t)(base + 5) * 32); }
        if (j == 1) { ap2 = *(const f32x4*)(asrc + (size_t)(base + 6) * 32); }
        if (j == 2) { ap3 = *(const f32x4*)(asrc + (size_t)(base + 7) * 32); }
      }
      short8 af[4];
#pragma unroll
      for (int rt = 0; rt < 4; ++rt) {
        int row = rt * 16 + l15;
        int off = row * GK + ((((j << 2) + quad + row) & 15) << 3);
        af[rt] = *(const short8*)&cbuf[off];
      }
#pragma unroll
      for (int rt = 0; rt < 4; ++rt)
#pragma unroll
        for (int ct = 0; ct < 4; ++ct)
          acc[rt][ct] = __builtin_amdgcn_mfma_f32_16x16x32_bf16(af[rt], bb[cu][ct], acc[rt][ct], 0, 0, 0);
      if (g + 1 < NG) {            // A writes into next buffer (late, loads have aged)
        if (j == 1) awr(nbuf, 0, ap0);
        if (j == 2) awr(nbuf, 1, ap1);
        if (j == 3) { awr(nbuf, 2, ap2); awr(nbuf, 3, ap3); }
      }
    }
    __syncthreads();
  }

  // ---- phase 2: scores s_t = sum_a v_a * tanh(wq_a + wm[t][a]) ----
  // C/D layout: col = lane&15 (a), row = quad*4 + reg (t)
  const float* wqb = wq + b * An;
  {
    float rs[4][4];
#pragma unroll
    for (int rt = 0; rt < 4; ++rt)
#pragma unroll
      for (int g2 = 0; g2 < 4; ++g2) rs[rt][g2] = 0.f;

#pragma unroll
    for (int ct = 0; ct < 4; ++ct) {
      const int a = w * 64 + ct * 16 + l15;
      const float wqa = wqb[a];
      const float va = Wv[a];
#pragma unroll
      for (int rt = 0; rt < 4; ++rt) {
#pragma unroll
        for (int g2 = 0; g2 < 4; ++g2) {
          float x = wqa + acc[rt][ct][g2];
          float ez = __expf(2.0f * x);
          float th = 1.0f - 2.0f * __builtin_amdgcn_rcpf(ez + 1.0f);
          rs[rt][g2] += va * th;
        }
      }
    }
#pragma unroll
    for (int rt = 0; rt < 4; ++rt) {
#pragma unroll
      for (int g2 = 0; g2 < 4; ++g2) {
        float v = rs[rt][g2];
        v += __shfl_xor(v, 1);
        v += __shfl_xor(v, 2);
        v += __shfl_xor(v, 4);
        v += __shfl_xor(v, 8);
        if (l15 == 0) atomicAdd(&s_score[rt * 16 + quad * 4 + g2], v);
      }
    }
  }
  __syncthreads();

  // ---- e_t, Z partial; write unnormalized alpha ----
  if (tid < RT) {
    float e = __expf(s_score[tid]);   // |s| <= 22.6, fp32-safe without max-sub
    s_e[tid] = e;
    out[(size_t)b * Tn + t0 + tid] = e;
    float z = e;
    z += __shfl_xor(z, 1);
    z += __shfl_xor(z, 2);
    z += __shfl_xor(z, 4);
    z += __shfl_xor(z, 8);
    z += __shfl_xor(z, 16);
    z += __shfl_xor(z, 32);
    if (lane == 0) atomicAdd(&Zacc[b], z);
  }
  __syncthreads();

  // ---- phase 3: context partial, re-read memory (fp32, L2/L3-hot) ----
  {
    const float* mrow = mem + ((size_t)(b * Tn + t0)) * Mn + 2 * tid;
    float c0 = 0.f, c1 = 0.f;
#pragma unroll 8
    for (int r = 0; r < RT; ++r) {
      f32x2 v = *(const f32x2*)(mrow + (size_t)r * Mn);
      float e = s_e[r];
      c0 += e * v.x;
      c1 += e * v.y;
    }
    if (partials) {   // no atomics: per-block partial row, reduced in finalize
      f32x2 o; o.x = c0; o.y = c1;
      *(f32x2*)(partials + ((size_t)((b << 5) + tt)) * Mn + 2 * tid) = o;
    } else {
      float* ctx = out + Bn * Tn + (size_t)b * Mn + 2 * tid;
      atomicAdd(&ctx[0], c0);
      atomicAdd(&ctx[1], c1);
    }
  }
}

// ---------------- finalize ----------------
__global__ void finalize_kernel(float* __restrict__ out, const float* __restrict__ Zacc) {
  int i = blockIdx.x * 256 + threadIdx.x;
  if (i < Bn * Tn) {
    out[i] /= Zacc[i >> 11];
  } else if (i < Bn * Tn + Bn * Mn) {
    int j = i - Bn * Tn;
    out[i] /= Zacc[j >> 10];
  }
}

__global__ void finalize_part_kernel(float* __restrict__ out, const float* __restrict__ Zacc,
                                     const float* __restrict__ partials) {
  int i = blockIdx.x * 256 + threadIdx.x;
  if (i < Bn * Tn) {
    out[i] /= Zacc[i >> 11];
  } else if (i < Bn * Tn + Bn * Mn) {
    int j = i - Bn * Tn;
    int bb2 = j >> 10;
    int m = j & (Mn - 1);
    const float* p = partials + (size_t)(bb2 << 5) * Mn + m;
    float s = 0.f;
#pragma unroll
    for (int t2 = 0; t2 < 32; ++t2) s += p[(size_t)t2 * Mn];
    out[i] = s / Zacc[bb2];
  }
}

extern "C" void kernel_launch(void* const* d_in, const int* in_sizes, int n_in,
                              void* d_out, int out_size, void* d_ws, size_t ws_size,
                              hipStream_t stream) {
  const float* query    = (const float*)d_in[0];  // [64,1024]
  const float* memory   = (const float*)d_in[1];  // [64,2048,1024]
  const float* W_query  = (const float*)d_in[2];  // [512,1024]
  const float* W_memory = (const float*)d_in[3];  // [512,1024]
  const float* W_v      = (const float*)d_in[4];  // [1,512]
  float* out = (float*)d_out;                     // alpha[64,2048] ++ context[64,1024]

  // ws: wq (128 KB) | Wmb bf16 (1 MB) | Zacc (256 B) | partials (8 MB, optional)
  const size_t off_wm = (size_t)Bn * An * 4;                 // 131072
  const size_t off_z  = off_wm + (size_t)An * Mn * 2;        // +1 MB
  const size_t off_p  = off_z + 256;
  const size_t need_p = off_p + (size_t)Bn * 32 * Mn * 4;    // + 8 MB
  float* wq = (float*)d_ws;
  unsigned short* Wmb = (unsigned short*)((char*)d_ws + off_wm);
  float* Zacc = (float*)((char*)d_ws + off_z);
  float* partials = (ws_size >= need_p) ? (float*)((char*)d_ws + off_p) : nullptr;

  zero_kernel<<<(Bn * Mn + Bn + 255) / 256, 256, 0, stream>>>(out + Bn * Tn, Zacc);
  cvt_wm_kernel<<<(An * Mn + 255) / 256, 256, 0, stream>>>(W_memory, Wmb);
  wq_kernel<<<Bn * 4, 128, 0, stream>>>(query, W_query, wq);
  fused_kernel<<<Bn * (Tn / RT), 512, 0, stream>>>(memory, wq, Wmb, W_v, out, Zacc, partials);
  if (partials)
    finalize_part_kernel<<<(Bn * Tn + Bn * Mn + 255) / 256, 256, 0, stream>>>(out, Zacc, partials);
  else
    finalize_kernel<<<(Bn * Tn + Bn * Mn + 255) / 256, 256, 0, stream>>>(out, Zacc);
}